// Round 1
// baseline (8772.816 us; speedup 1.0000x reference)
//
#include <hip/hip_runtime.h>
#include <math.h>

#define F 128
#define NLAYERS 2
#define BM 64
#define BN 64
#define BK 16

__device__ __forceinline__ float sigmoidf_(float x) { return 1.0f / (1.0f + expf(-x)); }

// ---------------------------------------------------------------------------
// Pack W_self/W_neigh [L][3][256][128] into GEMM-friendly layouts:
//   W1p [L][512][256]: k-parts (x, h, agg_x, agg_h), n = (gate r | gate u) x 128
//   W2p [L][512][128]: k-parts (x, rh, agg_x, agg_rh), n = gate c
// ---------------------------------------------------------------------------
__global__ void pack_w(const float* __restrict__ Wself, const float* __restrict__ Wneigh,
                       float* __restrict__ W1p, float* __restrict__ W2p) {
    int t = blockIdx.x * blockDim.x + threadIdx.x;
    const int n1 = 2 * 512 * 256;
    if (t < n1) {
        int n = t & 255;
        int k = (t >> 8) & 511;
        int l = t >> 17;
        int p = k >> 7, r = k & 127, g = n >> 7, c = n & 127;
        const float* Wsrc = (p < 2) ? Wself : Wneigh;
        W1p[t] = Wsrc[(((l * 3 + g) * 256) + ((p & 1) * 128 + r)) * 128 + c];
    } else {
        int t2 = t - n1;
        if (t2 >= 2 * 512 * 128) return;
        int n = t2 & 127;
        int k = (t2 >> 7) & 511;
        int l = t2 >> 16;
        int p = k >> 7, r = k & 127;
        const float* Wsrc = (p < 2) ? Wself : Wneigh;
        W2p[t2] = Wsrc[(((l * 3 + 2) * 256) + ((p & 1) * 128 + r)) * 128 + n];
    }
}

// ---------------------------------------------------------------------------
// Edge aggregation: agg[dst] += edge_w * V[src], atomics, float4 per thread.
// 32 threads per edge (128 features / 4).
// ---------------------------------------------------------------------------
__global__ void aggregate2(const float* __restrict__ V0, const float* __restrict__ V1,
                           const int* __restrict__ src, const int* __restrict__ dst,
                           const float* __restrict__ ew,
                           float* __restrict__ agg0, float* __restrict__ agg1, int nE) {
    int t = blockIdx.x * blockDim.x + threadIdx.x;
    int e = t >> 5;
    if (e >= nE) return;
    int f = (t & 31) << 2;
    int s = src[e], d = dst[e];
    float w = ew[e];
    const float4 v0 = *reinterpret_cast<const float4*>(V0 + (size_t)s * F + f);
    float* a0 = agg0 + (size_t)d * F + f;
    atomicAdd(a0 + 0, v0.x * w);
    atomicAdd(a0 + 1, v0.y * w);
    atomicAdd(a0 + 2, v0.z * w);
    atomicAdd(a0 + 3, v0.w * w);
    const float4 v1 = *reinterpret_cast<const float4*>(V1 + (size_t)s * F + f);
    float* a1 = agg1 + (size_t)d * F + f;
    atomicAdd(a1 + 0, v1.x * w);
    atomicAdd(a1 + 1, v1.y * w);
    atomicAdd(a1 + 2, v1.z * w);
    atomicAdd(a1 + 3, v1.w * w);
}

__global__ void aggregate1(const float* __restrict__ V0,
                           const int* __restrict__ src, const int* __restrict__ dst,
                           const float* __restrict__ ew,
                           float* __restrict__ agg0, int nE) {
    int t = blockIdx.x * blockDim.x + threadIdx.x;
    int e = t >> 5;
    if (e >= nE) return;
    int f = (t & 31) << 2;
    int s = src[e], d = dst[e];
    float w = ew[e];
    const float4 v0 = *reinterpret_cast<const float4*>(V0 + (size_t)s * F + f);
    float* a0 = agg0 + (size_t)d * F + f;
    atomicAdd(a0 + 0, v0.x * w);
    atomicAdd(a0 + 1, v0.y * w);
    atomicAdd(a0 + 2, v0.z * w);
    atomicAdd(a0 + 3, v0.w * w);
}

// ---------------------------------------------------------------------------
// GEMM1: [x | h | agg_x | agg_h] (N x 512) @ W1p (512 x 256) + bias -> sigmoid
//   cols 0..127  -> r; writes rh = r*h
//   cols 128..255-> u; writes u
// f32 tiled: BM=64 BN=64 BK=16, 256 threads, 4x4 microtile.
// ---------------------------------------------------------------------------
__global__ __launch_bounds__(256) void gemm_ru(
    const float* __restrict__ xin, const float* __restrict__ h,
    const float* __restrict__ aggx, const float* __restrict__ aggh,
    const float* __restrict__ W1p, const float* __restrict__ bias,
    float* __restrict__ rh, float* __restrict__ u, int Nnodes) {
    __shared__ float As[BK][BM];
    __shared__ float Bs[BK][BN];
    const float* parts[4] = {xin, h, aggx, aggh};
    int tid = threadIdx.x;
    int row0 = blockIdx.x * BM;
    int n0 = blockIdx.y * BN;
    int tx = tid & 15, ty = tid >> 4;
    float acc[4][4] = {};

    for (int ks = 0; ks < 512; ks += BK) {
        {
            int i = tid * 4;
            int m = i >> 4;
            int kk = i & 15;
            int grow = row0 + m;
            if (grow >= Nnodes) grow = Nnodes - 1;
            int kg = ks + kk;
            const float* P = parts[kg >> 7];
            float4 v = *reinterpret_cast<const float4*>(P + (size_t)grow * F + (kg & 127));
            As[kk + 0][m] = v.x;
            As[kk + 1][m] = v.y;
            As[kk + 2][m] = v.z;
            As[kk + 3][m] = v.w;
        }
        {
            int i = tid * 4;
            int kk = i >> 6;
            int n = i & 63;
            float4 v = *reinterpret_cast<const float4*>(W1p + (size_t)(ks + kk) * 256 + n0 + n);
            *reinterpret_cast<float4*>(&Bs[kk][n]) = v;
        }
        __syncthreads();
#pragma unroll
        for (int kk = 0; kk < BK; ++kk) {
            float a[4], b[4];
#pragma unroll
            for (int i = 0; i < 4; i++) a[i] = As[kk][ty * 4 + i];
#pragma unroll
            for (int j = 0; j < 4; j++) b[j] = Bs[kk][tx * 4 + j];
#pragma unroll
            for (int i = 0; i < 4; i++)
#pragma unroll
                for (int j = 0; j < 4; j++) acc[i][j] += a[i] * b[j];
        }
        __syncthreads();
    }

    for (int i = 0; i < 4; i++) {
        int row = row0 + ty * 4 + i;
        if (row >= Nnodes) break;
        for (int j = 0; j < 4; j++) {
            int n = n0 + tx * 4 + j;
            int gate = n >> 7, c = n & 127;
            float val = acc[i][j] + bias[gate * 128 + c];
            float sg = sigmoidf_(val);
            if (gate == 0)
                rh[(size_t)row * F + c] = sg * h[(size_t)row * F + c];
            else
                u[(size_t)row * F + c] = sg;
        }
    }
}

// ---------------------------------------------------------------------------
// GEMM2: [x | rh | agg_x | agg_rh] (N x 512) @ W2p (512 x 128) + bias -> c
// then h' = u*h + (1-u)*c, written to out1 (and out2 if non-null).
// ---------------------------------------------------------------------------
__global__ __launch_bounds__(256) void gemm_c(
    const float* __restrict__ xin, const float* __restrict__ rh,
    const float* __restrict__ aggx, const float* __restrict__ aggrh,
    const float* __restrict__ W2p, const float* __restrict__ bias2,
    const float* __restrict__ u, const float* __restrict__ h,
    float* __restrict__ out1, float* __restrict__ out2, int Nnodes) {
    __shared__ float As[BK][BM];
    __shared__ float Bs[BK][BN];
    const float* parts[4] = {xin, rh, aggx, aggrh};
    int tid = threadIdx.x;
    int row0 = blockIdx.x * BM;
    int n0 = blockIdx.y * BN;
    int tx = tid & 15, ty = tid >> 4;
    float acc[4][4] = {};

    for (int ks = 0; ks < 512; ks += BK) {
        {
            int i = tid * 4;
            int m = i >> 4;
            int kk = i & 15;
            int grow = row0 + m;
            if (grow >= Nnodes) grow = Nnodes - 1;
            int kg = ks + kk;
            const float* P = parts[kg >> 7];
            float4 v = *reinterpret_cast<const float4*>(P + (size_t)grow * F + (kg & 127));
            As[kk + 0][m] = v.x;
            As[kk + 1][m] = v.y;
            As[kk + 2][m] = v.z;
            As[kk + 3][m] = v.w;
        }
        {
            int i = tid * 4;
            int kk = i >> 6;
            int n = i & 63;
            float4 v = *reinterpret_cast<const float4*>(W2p + (size_t)(ks + kk) * 128 + n0 + n);
            *reinterpret_cast<float4*>(&Bs[kk][n]) = v;
        }
        __syncthreads();
#pragma unroll
        for (int kk = 0; kk < BK; ++kk) {
            float a[4], b[4];
#pragma unroll
            for (int i = 0; i < 4; i++) a[i] = As[kk][ty * 4 + i];
#pragma unroll
            for (int j = 0; j < 4; j++) b[j] = Bs[kk][tx * 4 + j];
#pragma unroll
            for (int i = 0; i < 4; i++)
#pragma unroll
                for (int j = 0; j < 4; j++) acc[i][j] += a[i] * b[j];
        }
        __syncthreads();
    }

    for (int i = 0; i < 4; i++) {
        int row = row0 + ty * 4 + i;
        if (row >= Nnodes) break;
        for (int j = 0; j < 4; j++) {
            int c = n0 + tx * 4 + j;  // gate c columns, 0..127
            float cval = sigmoidf_(acc[i][j] + bias2[c]);
            float uu = u[(size_t)row * F + c];
            float hh = h[(size_t)row * F + c];
            float hn = uu * hh + (1.0f - uu) * cval;
            out1[(size_t)row * F + c] = hn;
            if (out2) out2[(size_t)row * F + c] = hn;
        }
    }
}

// ---------------------------------------------------------------------------
extern "C" void kernel_launch(void* const* d_in, const int* in_sizes, int n_in,
                              void* d_out, int out_size, void* d_ws, size_t ws_size,
                              hipStream_t stream) {
    const float* x      = (const float*)d_in[0];
    const float* hidden = (const float*)d_in[1];
    const int*   src    = (const int*)d_in[2];
    const int*   dst    = (const int*)d_in[3];
    const float* ew     = (const float*)d_in[4];
    const float* Wself  = (const float*)d_in[5];
    const float* Wneigh = (const float*)d_in[6];
    const float* bias   = (const float*)d_in[7];
    float* out = (float*)d_out;

    int N = in_sizes[0] / F;  // 50000
    int E = in_sizes[2];      // 800000
    size_t NF = (size_t)N * F;

    float* ws     = (float*)d_ws;
    float* agg_x  = ws;
    float* agg_h  = agg_x + NF;
    float* agg_rh = agg_h + NF;
    float* rh     = agg_rh + NF;
    float* u      = rh + NF;
    float* W1p    = u + NF;
    float* W2p    = W1p + 2 * 512 * 256;

    pack_w<<<dim3(1536), dim3(256), 0, stream>>>(Wself, Wneigh, W1p, W2p);

    float* out_x  = out;
    float* out_h1 = out + NF;
    float* out_h2 = out + 2 * NF;

    int aggBlocks = (int)(((size_t)E * 32 + 255) / 256);
    const float* xin = x;
    for (int l = 0; l < NLAYERS; ++l) {
        const float* h = hidden + (size_t)l * NF;
        hipMemsetAsync(agg_x, 0, 2 * NF * sizeof(float), stream);
        aggregate2<<<dim3(aggBlocks), dim3(256), 0, stream>>>(xin, h, src, dst, ew, agg_x, agg_h, E);

        dim3 g1((N + BM - 1) / BM, 256 / BN);
        gemm_ru<<<g1, dim3(256), 0, stream>>>(xin, h, agg_x, agg_h,
                                              W1p + (size_t)l * 512 * 256,
                                              bias + (size_t)l * 3 * 128, rh, u, N);

        hipMemsetAsync(agg_rh, 0, NF * sizeof(float), stream);
        aggregate1<<<dim3(aggBlocks), dim3(256), 0, stream>>>(rh, src, dst, ew, agg_rh, E);

        float* o1 = (l == 0) ? out_h1 : out_h2;
        float* o2 = (l == NLAYERS - 1) ? out_x : nullptr;
        dim3 g2((N + BM - 1) / BM, 128 / BN);
        gemm_c<<<g2, dim3(256), 0, stream>>>(xin, rh, agg_x, agg_rh,
                                             W2p + (size_t)l * 512 * 128,
                                             bias + (size_t)l * 3 * 128 + 256,
                                             u, h, o1, o2, N);
        xin = o1;
    }
}

// Round 2
// 1197.994 us; speedup vs baseline: 7.3229x; 7.3229x over previous
//
#include <hip/hip_runtime.h>
#include <math.h>

#define F 128
#define NLAYERS 2
#define BM 64
#define BN 64
#define BK 16

__device__ __forceinline__ float sigmoidf_(float x) { return 1.0f / (1.0f + expf(-x)); }

// ---------------------------------------------------------------------------
// Pack W_self/W_neigh [L][3][256][128] into GEMM-friendly layouts:
//   W1p [L][512][256]: k-parts (x, h, agg_x, agg_h), n = (gate r | gate u) x 128
//   W2p [L][512][128]: k-parts (x, rh, agg_x, agg_rh), n = gate c
// ---------------------------------------------------------------------------
__global__ void pack_w(const float* __restrict__ Wself, const float* __restrict__ Wneigh,
                       float* __restrict__ W1p, float* __restrict__ W2p) {
    int t = blockIdx.x * blockDim.x + threadIdx.x;
    const int n1 = 2 * 512 * 256;
    if (t < n1) {
        int n = t & 255;
        int k = (t >> 8) & 511;
        int l = t >> 17;
        int p = k >> 7, r = k & 127, g = n >> 7, c = n & 127;
        const float* Wsrc = (p < 2) ? Wself : Wneigh;
        W1p[t] = Wsrc[(((l * 3 + g) * 256) + ((p & 1) * 128 + r)) * 128 + c];
    } else {
        int t2 = t - n1;
        if (t2 >= 2 * 512 * 128) return;
        int n = t2 & 127;
        int k = (t2 >> 7) & 511;
        int l = t2 >> 16;
        int p = k >> 7, r = k & 127;
        const float* Wsrc = (p < 2) ? Wself : Wneigh;
        W2p[t2] = Wsrc[(((l * 3 + 2) * 256) + ((p & 1) * 128 + r)) * 128 + n];
    }
}

// ---------------------------------------------------------------------------
// CSR build: histogram by dst -> exclusive scan -> scatter (src, w) sorted.
// Built once per call; reused by all 6 aggregation passes (edges are static).
// ---------------------------------------------------------------------------
__global__ void hist_dst(const int* __restrict__ dst, int* __restrict__ cnt, int E) {
    int e = blockIdx.x * blockDim.x + threadIdx.x;
    if (e < E) atomicAdd(&cnt[dst[e]], 1);
}

// Single-block (1024 thr) exclusive scan over n counts -> offs[0..n], cursor copy.
__global__ __launch_bounds__(1024) void scan_offs(const int* __restrict__ cnt,
                                                  int* __restrict__ offs,
                                                  int* __restrict__ cursor, int n) {
    __shared__ int wsum[16];
    __shared__ int carry_s;
    int tid = threadIdx.x;
    int lane = tid & 63, wid = tid >> 6;
    if (tid == 0) carry_s = 0;
    __syncthreads();
    for (int base = 0; base < n; base += 1024) {
        int i = base + tid;
        int v = (i < n) ? cnt[i] : 0;
        int incl = v;
#pragma unroll
        for (int off = 1; off < 64; off <<= 1) {
            int t = __shfl_up(incl, off, 64);
            if (lane >= off) incl += t;
        }
        if (lane == 63) wsum[wid] = incl;
        __syncthreads();
        if (wid == 0) {
            int s = (lane < 16) ? wsum[lane] : 0;
#pragma unroll
            for (int off = 1; off < 16; off <<= 1) {
                int t = __shfl_up(s, off, 64);
                if (lane >= off) s += t;
            }
            if (lane < 16) wsum[lane] = s;
        }
        __syncthreads();
        int wbase = (wid > 0) ? wsum[wid - 1] : 0;
        int carry = carry_s;
        int excl = carry + wbase + incl - v;
        if (i < n) { offs[i] = excl; cursor[i] = excl; }
        __syncthreads();
        if (tid == 1023) carry_s = carry + wsum[15];
        __syncthreads();
    }
    if (threadIdx.x == 0) offs[n] = carry_s;
}

__global__ void scatter_edges(const int* __restrict__ src, const int* __restrict__ dst,
                              const float* __restrict__ ew, int* __restrict__ cursor,
                              int2* __restrict__ es, int E) {
    int e = blockIdx.x * blockDim.x + threadIdx.x;
    if (e >= E) return;
    int d = dst[e];
    int p = atomicAdd(&cursor[d], 1);
    es[p] = make_int2(src[e], __float_as_int(ew[e]));
}

// ---------------------------------------------------------------------------
// CSR aggregation: 32 lanes per node (float4/lane), registers accumulate,
// one coalesced 512B store per node per table. No atomics.
// ---------------------------------------------------------------------------
__global__ __launch_bounds__(256) void agg_csr2(
    const float* __restrict__ V0, const float* __restrict__ V1,
    const int2* __restrict__ es, const int* __restrict__ offs,
    float* __restrict__ agg0, float* __restrict__ agg1, int N) {
    int node = blockIdx.x * 8 + (threadIdx.x >> 5);
    if (node >= N) return;
    int lane = threadIdx.x & 31;
    int beg = offs[node], end = offs[node + 1];
    float4 a0 = make_float4(0.f, 0.f, 0.f, 0.f);
    float4 a1 = a0;
    for (int i = beg; i < end; ++i) {
        int2 sw = es[i];
        float w = __int_as_float(sw.y);
        size_t rb = (size_t)sw.x * F + lane * 4;
        float4 v0 = *reinterpret_cast<const float4*>(V0 + rb);
        float4 v1 = *reinterpret_cast<const float4*>(V1 + rb);
        a0.x += w * v0.x; a0.y += w * v0.y; a0.z += w * v0.z; a0.w += w * v0.w;
        a1.x += w * v1.x; a1.y += w * v1.y; a1.z += w * v1.z; a1.w += w * v1.w;
    }
    size_t ob = (size_t)node * F + lane * 4;
    *reinterpret_cast<float4*>(agg0 + ob) = a0;
    *reinterpret_cast<float4*>(agg1 + ob) = a1;
}

__global__ __launch_bounds__(256) void agg_csr1(
    const float* __restrict__ V0,
    const int2* __restrict__ es, const int* __restrict__ offs,
    float* __restrict__ agg0, int N) {
    int node = blockIdx.x * 8 + (threadIdx.x >> 5);
    if (node >= N) return;
    int lane = threadIdx.x & 31;
    int beg = offs[node], end = offs[node + 1];
    float4 a0 = make_float4(0.f, 0.f, 0.f, 0.f);
    for (int i = beg; i < end; ++i) {
        int2 sw = es[i];
        float w = __int_as_float(sw.y);
        size_t rb = (size_t)sw.x * F + lane * 4;
        float4 v0 = *reinterpret_cast<const float4*>(V0 + rb);
        a0.x += w * v0.x; a0.y += w * v0.y; a0.z += w * v0.z; a0.w += w * v0.w;
    }
    size_t ob = (size_t)node * F + lane * 4;
    *reinterpret_cast<float4*>(agg0 + ob) = a0;
}

// ---------------------------------------------------------------------------
// GEMM1: [x | h | agg_x | agg_h] (N x 512) @ W1p (512 x 256) + bias -> sigmoid
//   cols 0..127  -> r; writes rh = r*h
//   cols 128..255-> u; writes u
// ---------------------------------------------------------------------------
__global__ __launch_bounds__(256) void gemm_ru(
    const float* __restrict__ xin, const float* __restrict__ h,
    const float* __restrict__ aggx, const float* __restrict__ aggh,
    const float* __restrict__ W1p, const float* __restrict__ bias,
    float* __restrict__ rh, float* __restrict__ u, int Nnodes) {
    __shared__ float As[BK][BM];
    __shared__ float Bs[BK][BN];
    const float* parts[4] = {xin, h, aggx, aggh};
    int tid = threadIdx.x;
    int row0 = blockIdx.x * BM;
    int n0 = blockIdx.y * BN;
    int tx = tid & 15, ty = tid >> 4;
    float acc[4][4] = {};

    for (int ks = 0; ks < 512; ks += BK) {
        {
            int i = tid * 4;
            int m = i >> 4;
            int kk = i & 15;
            int grow = row0 + m;
            if (grow >= Nnodes) grow = Nnodes - 1;
            int kg = ks + kk;
            const float* P = parts[kg >> 7];
            float4 v = *reinterpret_cast<const float4*>(P + (size_t)grow * F + (kg & 127));
            As[kk + 0][m] = v.x;
            As[kk + 1][m] = v.y;
            As[kk + 2][m] = v.z;
            As[kk + 3][m] = v.w;
        }
        {
            int i = tid * 4;
            int kk = i >> 6;
            int n = i & 63;
            float4 v = *reinterpret_cast<const float4*>(W1p + (size_t)(ks + kk) * 256 + n0 + n);
            *reinterpret_cast<float4*>(&Bs[kk][n]) = v;
        }
        __syncthreads();
#pragma unroll
        for (int kk = 0; kk < BK; ++kk) {
            float a[4], b[4];
#pragma unroll
            for (int i = 0; i < 4; i++) a[i] = As[kk][ty * 4 + i];
#pragma unroll
            for (int j = 0; j < 4; j++) b[j] = Bs[kk][tx * 4 + j];
#pragma unroll
            for (int i = 0; i < 4; i++)
#pragma unroll
                for (int j = 0; j < 4; j++) acc[i][j] += a[i] * b[j];
        }
        __syncthreads();
    }

    for (int i = 0; i < 4; i++) {
        int row = row0 + ty * 4 + i;
        if (row >= Nnodes) break;
        for (int j = 0; j < 4; j++) {
            int n = n0 + tx * 4 + j;
            int gate = n >> 7, c = n & 127;
            float val = acc[i][j] + bias[gate * 128 + c];
            float sg = sigmoidf_(val);
            if (gate == 0)
                rh[(size_t)row * F + c] = sg * h[(size_t)row * F + c];
            else
                u[(size_t)row * F + c] = sg;
        }
    }
}

// ---------------------------------------------------------------------------
// GEMM2: [x | rh | agg_x | agg_rh] (N x 512) @ W2p (512 x 128) + bias -> c
// then h' = u*h + (1-u)*c, written to out1 (and out2 if non-null).
// ---------------------------------------------------------------------------
__global__ __launch_bounds__(256) void gemm_c(
    const float* __restrict__ xin, const float* __restrict__ rh,
    const float* __restrict__ aggx, const float* __restrict__ aggrh,
    const float* __restrict__ W2p, const float* __restrict__ bias2,
    const float* __restrict__ u, const float* __restrict__ h,
    float* __restrict__ out1, float* __restrict__ out2, int Nnodes) {
    __shared__ float As[BK][BM];
    __shared__ float Bs[BK][BN];
    const float* parts[4] = {xin, rh, aggx, aggrh};
    int tid = threadIdx.x;
    int row0 = blockIdx.x * BM;
    int n0 = blockIdx.y * BN;
    int tx = tid & 15, ty = tid >> 4;
    float acc[4][4] = {};

    for (int ks = 0; ks < 512; ks += BK) {
        {
            int i = tid * 4;
            int m = i >> 4;
            int kk = i & 15;
            int grow = row0 + m;
            if (grow >= Nnodes) grow = Nnodes - 1;
            int kg = ks + kk;
            const float* P = parts[kg >> 7];
            float4 v = *reinterpret_cast<const float4*>(P + (size_t)grow * F + (kg & 127));
            As[kk + 0][m] = v.x;
            As[kk + 1][m] = v.y;
            As[kk + 2][m] = v.z;
            As[kk + 3][m] = v.w;
        }
        {
            int i = tid * 4;
            int kk = i >> 6;
            int n = i & 63;
            float4 v = *reinterpret_cast<const float4*>(W2p + (size_t)(ks + kk) * 128 + n0 + n);
            *reinterpret_cast<float4*>(&Bs[kk][n]) = v;
        }
        __syncthreads();
#pragma unroll
        for (int kk = 0; kk < BK; ++kk) {
            float a[4], b[4];
#pragma unroll
            for (int i = 0; i < 4; i++) a[i] = As[kk][ty * 4 + i];
#pragma unroll
            for (int j = 0; j < 4; j++) b[j] = Bs[kk][tx * 4 + j];
#pragma unroll
            for (int i = 0; i < 4; i++)
#pragma unroll
                for (int j = 0; j < 4; j++) acc[i][j] += a[i] * b[j];
        }
        __syncthreads();
    }

    for (int i = 0; i < 4; i++) {
        int row = row0 + ty * 4 + i;
        if (row >= Nnodes) break;
        for (int j = 0; j < 4; j++) {
            int c = n0 + tx * 4 + j;  // gate c columns, 0..127
            float cval = sigmoidf_(acc[i][j] + bias2[c]);
            float uu = u[(size_t)row * F + c];
            float hh = h[(size_t)row * F + c];
            float hn = uu * hh + (1.0f - uu) * cval;
            out1[(size_t)row * F + c] = hn;
            if (out2) out2[(size_t)row * F + c] = hn;
        }
    }
}

// ---------------------------------------------------------------------------
extern "C" void kernel_launch(void* const* d_in, const int* in_sizes, int n_in,
                              void* d_out, int out_size, void* d_ws, size_t ws_size,
                              hipStream_t stream) {
    const float* x      = (const float*)d_in[0];
    const float* hidden = (const float*)d_in[1];
    const int*   src    = (const int*)d_in[2];
    const int*   dst    = (const int*)d_in[3];
    const float* ew     = (const float*)d_in[4];
    const float* Wself  = (const float*)d_in[5];
    const float* Wneigh = (const float*)d_in[6];
    const float* bias   = (const float*)d_in[7];
    float* out = (float*)d_out;

    int N = in_sizes[0] / F;  // 50000
    int E = in_sizes[2];      // 800000
    size_t NF = (size_t)N * F;

    float* ws     = (float*)d_ws;
    float* agg_x  = ws;
    float* agg_h  = agg_x + NF;
    float* agg_rh = agg_h + NF;
    float* rh     = agg_rh + NF;
    float* u      = rh + NF;
    float* W1p    = u + NF;
    float* W2p    = W1p + 2 * 512 * 256;
    int2*  es     = (int2*)(W2p + 2 * 512 * 128);
    int*   cnt    = (int*)(es + E);
    int*   offs   = cnt + N;
    int*   cursor = offs + (N + 2);  // offs has N+1 entries (+1 pad)

    pack_w<<<dim3(1536), dim3(256), 0, stream>>>(Wself, Wneigh, W1p, W2p);

    // CSR build (once per call; edges are layer-invariant)
    hipMemsetAsync(cnt, 0, (size_t)N * sizeof(int), stream);
    int eBlocks = (E + 255) / 256;
    hist_dst<<<dim3(eBlocks), dim3(256), 0, stream>>>(dst, cnt, E);
    scan_offs<<<dim3(1), dim3(1024), 0, stream>>>(cnt, offs, cursor, N);
    scatter_edges<<<dim3(eBlocks), dim3(256), 0, stream>>>(src, dst, ew, cursor, es, E);

    float* out_x  = out;
    float* out_h1 = out + NF;
    float* out_h2 = out + 2 * NF;

    int aggBlocks = (N + 7) / 8;
    const float* xin = x;
    for (int l = 0; l < NLAYERS; ++l) {
        const float* h = hidden + (size_t)l * NF;
        agg_csr2<<<dim3(aggBlocks), dim3(256), 0, stream>>>(xin, h, es, offs, agg_x, agg_h, N);

        dim3 g1((N + BM - 1) / BM, 256 / BN);
        gemm_ru<<<g1, dim3(256), 0, stream>>>(xin, h, agg_x, agg_h,
                                              W1p + (size_t)l * 512 * 256,
                                              bias + (size_t)l * 3 * 128, rh, u, N);

        agg_csr1<<<dim3(aggBlocks), dim3(256), 0, stream>>>(rh, es, offs, agg_rh, N);

        float* o1 = (l == 0) ? out_h1 : out_h2;
        float* o2 = (l == NLAYERS - 1) ? out_x : nullptr;
        dim3 g2((N + BM - 1) / BM, 128 / BN);
        gemm_c<<<g2, dim3(256), 0, stream>>>(xin, rh, agg_x, agg_rh,
                                             W2p + (size_t)l * 512 * 128,
                                             bias + (size_t)l * 3 * 128 + 256,
                                             u, h, o1, o2, N);
        xin = o1;
    }
}

// Round 3
// 761.608 us; speedup vs baseline: 11.5188x; 1.5730x over previous
//
#include <hip/hip_runtime.h>
#include <math.h>

#define F 128
#define NLAYERS 2

typedef __attribute__((ext_vector_type(8))) short bf16x8s;
typedef __attribute__((ext_vector_type(4))) float f32x4;

__device__ __forceinline__ float sigmoidf_(float x) { return 1.0f / (1.0f + expf(-x)); }

__device__ __forceinline__ unsigned short f2bf(float f) {
    unsigned int u = __float_as_uint(f);
    u += 0x7fffu + ((u >> 16) & 1u);  // RNE
    return (unsigned short)(u >> 16);
}
__device__ __forceinline__ float bf2f(unsigned short s) {
    return __uint_as_float(((unsigned int)s) << 16);
}

// ---------------------------------------------------------------------------
// Weight pack: f32 [L][3][256][128] -> bf16 k-octet layout.
//  W1b [L][64][256][8]: gates (r|u) as 256 cols, K=512 parts (x,h,agg_x,agg_h)
//  W2b [L][64][128][8]: gate c, K parts (x, rh, agg_x, agg_rh)
// ---------------------------------------------------------------------------
__global__ void pack_w_bf16(const float* __restrict__ Ws, const float* __restrict__ Wn,
                            unsigned short* __restrict__ W1b, unsigned short* __restrict__ W2b) {
    int t = blockIdx.x * blockDim.x + threadIdx.x;
    const int n1 = 2 * 64 * 256 * 8;  // 262144
    if (t < n1) {
        int j = t & 7, n = (t >> 3) & 255, ko = (t >> 11) & 63, l = t >> 17;
        int k = ko * 8 + j;
        int p = k >> 7, r = k & 127, g = n >> 7, c = n & 127;
        const float* W = (p < 2) ? Ws : Wn;
        W1b[t] = f2bf(W[(((l * 3 + g) * 256) + ((p & 1) * 128 + r)) * 128 + c]);
    } else {
        int t2 = t - n1;
        if (t2 >= 2 * 64 * 128 * 8) return;
        int j = t2 & 7, n = (t2 >> 3) & 127, ko = (t2 >> 10) & 63, l = t2 >> 16;
        int k = ko * 8 + j;
        int p = k >> 7, r = k & 127;
        const float* W = (p < 2) ? Ws : Wn;
        W2b[t2] = f2bf(W[(((l * 3 + 2) * 256) + ((p & 1) * 128 + r)) * 128 + n]);
    }
}

// f32 -> bf16 row-major copy (float4 in, ushort4 out)
__global__ void cvt_bf16(const float* __restrict__ in, unsigned short* __restrict__ out, int n4) {
    int t = blockIdx.x * blockDim.x + threadIdx.x;
    if (t >= n4) return;
    float4 v = reinterpret_cast<const float4*>(in)[t];
    ushort4 o;
    o.x = f2bf(v.x); o.y = f2bf(v.y); o.z = f2bf(v.z); o.w = f2bf(v.w);
    reinterpret_cast<ushort4*>(out)[t] = o;
}

// ---------------------------------------------------------------------------
// CSR build (unchanged from R2)
// ---------------------------------------------------------------------------
__global__ void hist_dst(const int* __restrict__ dst, int* __restrict__ cnt, int E) {
    int e = blockIdx.x * blockDim.x + threadIdx.x;
    if (e < E) atomicAdd(&cnt[dst[e]], 1);
}

__global__ __launch_bounds__(1024) void scan_offs(const int* __restrict__ cnt,
                                                  int* __restrict__ offs,
                                                  int* __restrict__ cursor, int n) {
    __shared__ int wsum[16];
    __shared__ int carry_s;
    int tid = threadIdx.x;
    int lane = tid & 63, wid = tid >> 6;
    if (tid == 0) carry_s = 0;
    __syncthreads();
    for (int base = 0; base < n; base += 1024) {
        int i = base + tid;
        int v = (i < n) ? cnt[i] : 0;
        int incl = v;
#pragma unroll
        for (int off = 1; off < 64; off <<= 1) {
            int t = __shfl_up(incl, off, 64);
            if (lane >= off) incl += t;
        }
        if (lane == 63) wsum[wid] = incl;
        __syncthreads();
        if (wid == 0) {
            int s = (lane < 16) ? wsum[lane] : 0;
#pragma unroll
            for (int off = 1; off < 16; off <<= 1) {
                int t = __shfl_up(s, off, 64);
                if (lane >= off) s += t;
            }
            if (lane < 16) wsum[lane] = s;
        }
        __syncthreads();
        int wbase = (wid > 0) ? wsum[wid - 1] : 0;
        int carry = carry_s;
        int excl = carry + wbase + incl - v;
        if (i < n) { offs[i] = excl; cursor[i] = excl; }
        __syncthreads();
        if (tid == 1023) carry_s = carry + wsum[15];
        __syncthreads();
    }
    if (threadIdx.x == 0) offs[n] = carry_s;
}

__global__ void scatter_edges(const int* __restrict__ src, const int* __restrict__ dst,
                              const float* __restrict__ ew, int* __restrict__ cursor,
                              int2* __restrict__ es, int E) {
    int e = blockIdx.x * blockDim.x + threadIdx.x;
    if (e >= E) return;
    int d = dst[e];
    int p = atomicAdd(&cursor[d], 1);
    es[p] = make_int2(src[e], __float_as_int(ew[e]));
}

// ---------------------------------------------------------------------------
// CSR aggregation over bf16 tables: 32 lanes/node, ushort4 (8B) per lane,
// f32 accumulate, bf16 store. No atomics.
// ---------------------------------------------------------------------------
__global__ __launch_bounds__(256) void agg_csr2_b(
    const unsigned short* __restrict__ V0, const unsigned short* __restrict__ V1,
    const int2* __restrict__ es, const int* __restrict__ offs,
    unsigned short* __restrict__ agg0, unsigned short* __restrict__ agg1, int N) {
    int node = blockIdx.x * 8 + (threadIdx.x >> 5);
    if (node >= N) return;
    int lane = threadIdx.x & 31;
    int beg = offs[node], end = offs[node + 1];
    float a0x = 0, a0y = 0, a0z = 0, a0w = 0;
    float a1x = 0, a1y = 0, a1z = 0, a1w = 0;
    for (int i = beg; i < end; ++i) {
        int2 sw = es[i];
        float w = __int_as_float(sw.y);
        size_t rb = ((size_t)sw.x << 7) + (lane << 2);
        ushort4 v0 = *reinterpret_cast<const ushort4*>(V0 + rb);
        ushort4 v1 = *reinterpret_cast<const ushort4*>(V1 + rb);
        a0x += w * bf2f(v0.x); a0y += w * bf2f(v0.y);
        a0z += w * bf2f(v0.z); a0w += w * bf2f(v0.w);
        a1x += w * bf2f(v1.x); a1y += w * bf2f(v1.y);
        a1z += w * bf2f(v1.z); a1w += w * bf2f(v1.w);
    }
    size_t ob = ((size_t)node << 7) + (lane << 2);
    ushort4 o0, o1;
    o0.x = f2bf(a0x); o0.y = f2bf(a0y); o0.z = f2bf(a0z); o0.w = f2bf(a0w);
    o1.x = f2bf(a1x); o1.y = f2bf(a1y); o1.z = f2bf(a1z); o1.w = f2bf(a1w);
    *reinterpret_cast<ushort4*>(agg0 + ob) = o0;
    *reinterpret_cast<ushort4*>(agg1 + ob) = o1;
}

__global__ __launch_bounds__(256) void agg_csr1_b(
    const unsigned short* __restrict__ V0,
    const int2* __restrict__ es, const int* __restrict__ offs,
    unsigned short* __restrict__ agg0, int N) {
    int node = blockIdx.x * 8 + (threadIdx.x >> 5);
    if (node >= N) return;
    int lane = threadIdx.x & 31;
    int beg = offs[node], end = offs[node + 1];
    float a0x = 0, a0y = 0, a0z = 0, a0w = 0;
    for (int i = beg; i < end; ++i) {
        int2 sw = es[i];
        float w = __int_as_float(sw.y);
        size_t rb = ((size_t)sw.x << 7) + (lane << 2);
        ushort4 v0 = *reinterpret_cast<const ushort4*>(V0 + rb);
        a0x += w * bf2f(v0.x); a0y += w * bf2f(v0.y);
        a0z += w * bf2f(v0.z); a0w += w * bf2f(v0.w);
    }
    size_t ob = ((size_t)node << 7) + (lane << 2);
    ushort4 o0;
    o0.x = f2bf(a0x); o0.y = f2bf(a0y); o0.z = f2bf(a0z); o0.w = f2bf(a0w);
    *reinterpret_cast<ushort4*>(agg0 + ob) = o0;
}

// ---------------------------------------------------------------------------
// MFMA GEMM: A = [A0|A1|A2|A3] (N x 512, bf16 row-major 128 each),
// B = Wb (bf16 k-octet layout [K/8][Ntot][8]). 128x128 tile, 4 waves,
// 16x16x32 bf16 MFMA, 4x4 frags/wave. global_load_lds width-16 staging.
// mode 0 (gemm_ru): col<128 -> rhb = bf16(sigmoid*h); col>=128 -> u = sigmoid
// mode 1 (gemm_c):  c = sigmoid; hn = u*h+(1-u)*c -> outf (+outf2), outb=bf16(hn)
// ---------------------------------------------------------------------------
__global__ __launch_bounds__(256) void gemm_mfma(
    const unsigned short* __restrict__ A0, const unsigned short* __restrict__ A1,
    const unsigned short* __restrict__ A2, const unsigned short* __restrict__ A3,
    const unsigned short* __restrict__ Wb, const float* __restrict__ bias,
    const float* __restrict__ hfull, const float* __restrict__ uin,
    unsigned short* __restrict__ outb, float* __restrict__ outf,
    float* __restrict__ outf2, int Nn, int Ntot, int mode) {
    __shared__ __align__(16) unsigned short Als[4 * 128 * 8];  // [q][m][j]
    __shared__ __align__(16) unsigned short Bls[4 * 128 * 8];  // [q][n][j]
    const unsigned short* parts[4] = {A0, A1, A2, A3};

    int tid = threadIdx.x;
    int row0 = blockIdx.x * 128;
    int n0c = blockIdx.y * 128;
    int lane = tid & 63;
    int w = tid >> 6;
    int wbase = tid & 192;           // wave start (0,64,128,192)
    int wrow = (w & 1) << 6;
    int wcol = (w >> 1) << 6;
    int quad = lane >> 4, l16 = lane & 15;

    f32x4 acc[4][4];
    const f32x4 z4 = {0.f, 0.f, 0.f, 0.f};
#pragma unroll
    for (int mt = 0; mt < 4; ++mt)
#pragma unroll
        for (int nt = 0; nt < 4; ++nt) acc[mt][nt] = z4;

    for (int ks = 0; ks < 512; ks += 32) {
        const unsigned short* Apart = parts[ks >> 7];
        int cb = ks & 127;
#pragma unroll
        for (int b = 0; b < 2; ++b) {
            int idx = b * 256 + tid;
            int q = idx >> 7, m = idx & 127;
            int grow = row0 + m;
            if (grow >= Nn) grow = Nn - 1;
            const unsigned short* ga = Apart + ((size_t)grow << 7) + cb + (q << 3);
            unsigned short* la = &Als[(size_t)(b * 256 + wbase) * 8];
            __builtin_amdgcn_global_load_lds(
                (const __attribute__((address_space(1))) void*)ga,
                (__attribute__((address_space(3))) void*)la, 16, 0, 0);
        }
#pragma unroll
        for (int b = 0; b < 2; ++b) {
            int idx = b * 256 + tid;
            int q = idx >> 7, n = idx & 127;
            int koG = (ks >> 3) + q;
            const unsigned short* gb = Wb + ((size_t)(koG * Ntot + n0c + n) << 3);
            unsigned short* lb = &Bls[(size_t)(b * 256 + wbase) * 8];
            __builtin_amdgcn_global_load_lds(
                (const __attribute__((address_space(1))) void*)gb,
                (__attribute__((address_space(3))) void*)lb, 16, 0, 0);
        }
        __syncthreads();

        bf16x8s af[4], bf[4];
#pragma unroll
        for (int mt = 0; mt < 4; ++mt)
            af[mt] = *reinterpret_cast<const bf16x8s*>(
                &Als[(size_t)((quad << 7) + wrow + (mt << 4) + l16) << 3]);
#pragma unroll
        for (int nt = 0; nt < 4; ++nt)
            bf[nt] = *reinterpret_cast<const bf16x8s*>(
                &Bls[(size_t)((quad << 7) + wcol + (nt << 4) + l16) << 3]);
#pragma unroll
        for (int mt = 0; mt < 4; ++mt)
#pragma unroll
            for (int nt = 0; nt < 4; ++nt)
                acc[mt][nt] = __builtin_amdgcn_mfma_f32_16x16x32_bf16(
                    af[mt], bf[nt], acc[mt][nt], 0, 0, 0);
        __syncthreads();
    }

    // Epilogue: D[m][n]: row = quad*4+reg (+tiles), col = l16 (+tiles)
#pragma unroll
    for (int mt = 0; mt < 4; ++mt) {
#pragma unroll
        for (int reg = 0; reg < 4; ++reg) {
            int row = row0 + wrow + (mt << 4) + (quad << 2) + reg;
            if (row >= Nn) continue;
#pragma unroll
            for (int nt = 0; nt < 4; ++nt) {
                int col = n0c + wcol + (nt << 4) + l16;
                float val = acc[mt][nt][reg] + bias[col];
                if (mode == 0) {
                    float sg = sigmoidf_(val);
                    int c = col & 127;
                    size_t o = ((size_t)row << 7) + c;
                    if (col < 128)
                        outb[o] = f2bf(sg * hfull[o]);   // rh = r*h (bf16)
                    else
                        outf[o] = sg;                    // u (f32)
                } else {
                    float cv = sigmoidf_(val);
                    size_t o = ((size_t)row << 7) + col;
                    float uu = uin[o];
                    float hh = hfull[o];
                    float hn = uu * hh + (1.0f - uu) * cv;
                    outf[o] = hn;
                    if (outf2) outf2[o] = hn;
                    outb[o] = f2bf(hn);                  // next layer's xb
                }
            }
        }
    }
}

// ---------------------------------------------------------------------------
extern "C" void kernel_launch(void* const* d_in, const int* in_sizes, int n_in,
                              void* d_out, int out_size, void* d_ws, size_t ws_size,
                              hipStream_t stream) {
    const float* x      = (const float*)d_in[0];
    const float* hidden = (const float*)d_in[1];
    const int*   src    = (const int*)d_in[2];
    const int*   dst    = (const int*)d_in[3];
    const float* ew     = (const float*)d_in[4];
    const float* Wself  = (const float*)d_in[5];
    const float* Wneigh = (const float*)d_in[6];
    const float* bias   = (const float*)d_in[7];
    float* out = (float*)d_out;

    int N = in_sizes[0] / F;  // 50000
    int E = in_sizes[2];      // 800000
    size_t NF = (size_t)N * F;

    char* p = (char*)d_ws;
    auto alloc = [&](size_t bytes) { char* r = p; p += (bytes + 255) & ~255ull; return r; };
    unsigned short* xb0    = (unsigned short*)alloc(NF * 2);
    unsigned short* xb1    = (unsigned short*)alloc(NF * 2);
    unsigned short* hb     = (unsigned short*)alloc(2 * NF * 2);   // hb0, hb1
    unsigned short* agg_xb = (unsigned short*)alloc(NF * 2);
    unsigned short* agg_hb = (unsigned short*)alloc(NF * 2);
    unsigned short* agg_rb = (unsigned short*)alloc(NF * 2);
    unsigned short* rhb    = (unsigned short*)alloc(NF * 2);
    float*          u      = (float*)alloc(NF * 4);
    unsigned short* W1b    = (unsigned short*)alloc(2 * 64 * 256 * 8 * 2);
    unsigned short* W2b    = (unsigned short*)alloc(2 * 64 * 128 * 8 * 2);
    int2*           es     = (int2*)alloc((size_t)E * 8);
    int*            cnt    = (int*)alloc((size_t)N * 4);
    int*            offs   = (int*)alloc(((size_t)N + 1) * 4);
    int*            cursor = (int*)alloc((size_t)N * 4);

    pack_w_bf16<<<dim3(1536), dim3(256), 0, stream>>>(Wself, Wneigh, W1b, W2b);
    cvt_bf16<<<dim3((int)(NF / 4 + 255) / 256, 1), dim3(256), 0, stream>>>(x, xb0, (int)(NF / 4));
    cvt_bf16<<<dim3((int)(2 * NF / 4 + 255) / 256, 1), dim3(256), 0, stream>>>(hidden, hb, (int)(2 * NF / 4));

    hipMemsetAsync(cnt, 0, (size_t)N * sizeof(int), stream);
    int eBlocks = (E + 255) / 256;
    hist_dst<<<dim3(eBlocks), dim3(256), 0, stream>>>(dst, cnt, E);
    scan_offs<<<dim3(1), dim3(1024), 0, stream>>>(cnt, offs, cursor, N);
    scatter_edges<<<dim3(eBlocks), dim3(256), 0, stream>>>(src, dst, ew, cursor, es, E);

    float* out_x  = out;
    float* out_h1 = out + NF;
    float* out_h2 = out + 2 * NF;

    int aggBlocks = (N + 7) / 8;
    int mBlocks = (N + 127) / 128;
    for (int l = 0; l < NLAYERS; ++l) {
        const unsigned short* xbL = (l == 0) ? xb0 : xb1;
        const unsigned short* hbL = hb + (size_t)l * NF;
        const float* hL = hidden + (size_t)l * NF;
        const float* biasL = bias + (size_t)l * 384;

        agg_csr2_b<<<dim3(aggBlocks), dim3(256), 0, stream>>>(xbL, hbL, es, offs,
                                                              agg_xb, agg_hb, N);

        gemm_mfma<<<dim3(mBlocks, 2), dim3(256), 0, stream>>>(
            xbL, hbL, agg_xb, agg_hb,
            W1b + (size_t)l * 64 * 256 * 8, biasL, hL, nullptr,
            rhb, u, nullptr, N, 256, 0);

        agg_csr1_b<<<dim3(aggBlocks), dim3(256), 0, stream>>>(rhb, es, offs, agg_rb, N);

        float* o1 = (l == 0) ? out_h1 : out_h2;
        float* o2 = (l == NLAYERS - 1) ? out_x : nullptr;
        unsigned short* xbN = (l == 0) ? xb1 : xb0;  // l==1's outb is a dead scratch
        gemm_mfma<<<dim3(mBlocks, 1), dim3(256), 0, stream>>>(
            xbL, rhb, agg_xb, agg_rb,
            W2b + (size_t)l * 64 * 128 * 8, biasL + 256, hL, u,
            xbN, o1, o2, N, 128, 1);
    }
}

// Round 4
// 664.058 us; speedup vs baseline: 13.2109x; 1.1469x over previous
//
#include <hip/hip_runtime.h>
#include <math.h>

#define F 128
#define NLAYERS 2

typedef __attribute__((ext_vector_type(8))) short bf16x8s;
typedef __attribute__((ext_vector_type(4))) float f32x4;

__device__ __forceinline__ float sigmoidf_(float x) { return 1.0f / (1.0f + expf(-x)); }

__device__ __forceinline__ unsigned short f2bf(float f) {
    unsigned int u = __float_as_uint(f);
    u += 0x7fffu + ((u >> 16) & 1u);  // RNE
    return (unsigned short)(u >> 16);
}
__device__ __forceinline__ float bf2f(unsigned short s) {
    return __uint_as_float(((unsigned int)s) << 16);
}

// ---------------------------------------------------------------------------
// Weight pack: f32 [L][3][256][128] -> bf16 k-octet layout.
//  W1b [L][64][256][8]: gates (r|u) as 256 cols, K=512 parts (x,h,agg_x,agg_h)
//  W2b [L][64][128][8]: gate c, K parts (x, rh, agg_x, agg_rh)
// ---------------------------------------------------------------------------
__global__ void pack_w_bf16(const float* __restrict__ Ws, const float* __restrict__ Wn,
                            unsigned short* __restrict__ W1b, unsigned short* __restrict__ W2b) {
    int t = blockIdx.x * blockDim.x + threadIdx.x;
    const int n1 = 2 * 64 * 256 * 8;  // 262144
    if (t < n1) {
        int j = t & 7, n = (t >> 3) & 255, ko = (t >> 11) & 63, l = t >> 17;
        int k = ko * 8 + j;
        int p = k >> 7, r = k & 127, g = n >> 7, c = n & 127;
        const float* W = (p < 2) ? Ws : Wn;
        W1b[t] = f2bf(W[(((l * 3 + g) * 256) + ((p & 1) * 128 + r)) * 128 + c]);
    } else {
        int t2 = t - n1;
        if (t2 >= 2 * 64 * 128 * 8) return;
        int j = t2 & 7, n = (t2 >> 3) & 127, ko = (t2 >> 10) & 63, l = t2 >> 16;
        int k = ko * 8 + j;
        int p = k >> 7, r = k & 127;
        const float* W = (p < 2) ? Ws : Wn;
        W2b[t2] = f2bf(W[(((l * 3 + 2) * 256) + ((p & 1) * 128 + r)) * 128 + n]);
    }
}

// f32 -> bf16 row-major copy (float4 in, ushort4 out)
__global__ void cvt_bf16(const float* __restrict__ in, unsigned short* __restrict__ out, int n4) {
    int t = blockIdx.x * blockDim.x + threadIdx.x;
    if (t >= n4) return;
    float4 v = reinterpret_cast<const float4*>(in)[t];
    ushort4 o;
    o.x = f2bf(v.x); o.y = f2bf(v.y); o.z = f2bf(v.z); o.w = f2bf(v.w);
    reinterpret_cast<ushort4*>(out)[t] = o;
}

// ---------------------------------------------------------------------------
// CSR build
// ---------------------------------------------------------------------------
__global__ void hist_dst(const int* __restrict__ dst, int* __restrict__ cnt, int E) {
    int e = blockIdx.x * blockDim.x + threadIdx.x;
    if (e < E) atomicAdd(&cnt[dst[e]], 1);
}

__global__ __launch_bounds__(1024) void scan_offs(const int* __restrict__ cnt,
                                                  int* __restrict__ offs,
                                                  int* __restrict__ cursor, int n) {
    __shared__ int wsum[16];
    __shared__ int carry_s;
    int tid = threadIdx.x;
    int lane = tid & 63, wid = tid >> 6;
    if (tid == 0) carry_s = 0;
    __syncthreads();
    for (int base = 0; base < n; base += 1024) {
        int i = base + tid;
        int v = (i < n) ? cnt[i] : 0;
        int incl = v;
#pragma unroll
        for (int off = 1; off < 64; off <<= 1) {
            int t = __shfl_up(incl, off, 64);
            if (lane >= off) incl += t;
        }
        if (lane == 63) wsum[wid] = incl;
        __syncthreads();
        if (wid == 0) {
            int s = (lane < 16) ? wsum[lane] : 0;
#pragma unroll
            for (int off = 1; off < 16; off <<= 1) {
                int t = __shfl_up(s, off, 64);
                if (lane >= off) s += t;
            }
            if (lane < 16) wsum[lane] = s;
        }
        __syncthreads();
        int wbase = (wid > 0) ? wsum[wid - 1] : 0;
        int carry = carry_s;
        int excl = carry + wbase + incl - v;
        if (i < n) { offs[i] = excl; cursor[i] = excl; }
        __syncthreads();
        if (tid == 1023) carry_s = carry + wsum[15];
        __syncthreads();
    }
    if (threadIdx.x == 0) offs[n] = carry_s;
}

__global__ void scatter_edges(const int* __restrict__ src, const int* __restrict__ dst,
                              const float* __restrict__ ew, int* __restrict__ cursor,
                              int2* __restrict__ es, int E) {
    int e = blockIdx.x * blockDim.x + threadIdx.x;
    if (e >= E) return;
    int d = dst[e];
    int p = atomicAdd(&cursor[d], 1);
    es[p] = make_int2(src[e], __float_as_int(ew[e]));
}

// ---------------------------------------------------------------------------
// CSR aggregation over bf16 tables: 32 lanes/node, ushort4 (8B) per lane,
// unroll-2 with dual accumulators for MLP. f32 accumulate, bf16 store.
// ---------------------------------------------------------------------------
__global__ __launch_bounds__(256) void agg_csr2_b(
    const unsigned short* __restrict__ V0, const unsigned short* __restrict__ V1,
    const int2* __restrict__ es, const int* __restrict__ offs,
    unsigned short* __restrict__ agg0, unsigned short* __restrict__ agg1, int N) {
    int node = blockIdx.x * 8 + (threadIdx.x >> 5);
    if (node >= N) return;
    int lane = threadIdx.x & 31;
    int beg = offs[node], end = offs[node + 1];
    float p0[4] = {0, 0, 0, 0}, q0[4] = {0, 0, 0, 0};
    float p1[4] = {0, 0, 0, 0}, q1[4] = {0, 0, 0, 0};
    int i = beg;
    for (; i + 1 < end; i += 2) {
        int2 e0 = es[i], e1 = es[i + 1];
        float w0 = __int_as_float(e0.y), w1 = __int_as_float(e1.y);
        size_t r0 = ((size_t)e0.x << 7) + (lane << 2);
        size_t r1 = ((size_t)e1.x << 7) + (lane << 2);
        ushort4 x0 = *reinterpret_cast<const ushort4*>(V0 + r0);
        ushort4 x1 = *reinterpret_cast<const ushort4*>(V0 + r1);
        ushort4 h0 = *reinterpret_cast<const ushort4*>(V1 + r0);
        ushort4 h1 = *reinterpret_cast<const ushort4*>(V1 + r1);
        p0[0] += w0 * bf2f(x0.x); p0[1] += w0 * bf2f(x0.y);
        p0[2] += w0 * bf2f(x0.z); p0[3] += w0 * bf2f(x0.w);
        p1[0] += w1 * bf2f(x1.x); p1[1] += w1 * bf2f(x1.y);
        p1[2] += w1 * bf2f(x1.z); p1[3] += w1 * bf2f(x1.w);
        q0[0] += w0 * bf2f(h0.x); q0[1] += w0 * bf2f(h0.y);
        q0[2] += w0 * bf2f(h0.z); q0[3] += w0 * bf2f(h0.w);
        q1[0] += w1 * bf2f(h1.x); q1[1] += w1 * bf2f(h1.y);
        q1[2] += w1 * bf2f(h1.z); q1[3] += w1 * bf2f(h1.w);
    }
    if (i < end) {
        int2 e0 = es[i];
        float w0 = __int_as_float(e0.y);
        size_t r0 = ((size_t)e0.x << 7) + (lane << 2);
        ushort4 x0 = *reinterpret_cast<const ushort4*>(V0 + r0);
        ushort4 h0 = *reinterpret_cast<const ushort4*>(V1 + r0);
        p0[0] += w0 * bf2f(x0.x); p0[1] += w0 * bf2f(x0.y);
        p0[2] += w0 * bf2f(x0.z); p0[3] += w0 * bf2f(x0.w);
        q0[0] += w0 * bf2f(h0.x); q0[1] += w0 * bf2f(h0.y);
        q0[2] += w0 * bf2f(h0.z); q0[3] += w0 * bf2f(h0.w);
    }
    size_t ob = ((size_t)node << 7) + (lane << 2);
    ushort4 o0, o1;
    o0.x = f2bf(p0[0] + p1[0]); o0.y = f2bf(p0[1] + p1[1]);
    o0.z = f2bf(p0[2] + p1[2]); o0.w = f2bf(p0[3] + p1[3]);
    o1.x = f2bf(q0[0] + q1[0]); o1.y = f2bf(q0[1] + q1[1]);
    o1.z = f2bf(q0[2] + q1[2]); o1.w = f2bf(q0[3] + q1[3]);
    *reinterpret_cast<ushort4*>(agg0 + ob) = o0;
    *reinterpret_cast<ushort4*>(agg1 + ob) = o1;
}

__global__ __launch_bounds__(256) void agg_csr1_b(
    const unsigned short* __restrict__ V0,
    const int2* __restrict__ es, const int* __restrict__ offs,
    unsigned short* __restrict__ agg0, int N) {
    int node = blockIdx.x * 8 + (threadIdx.x >> 5);
    if (node >= N) return;
    int lane = threadIdx.x & 31;
    int beg = offs[node], end = offs[node + 1];
    float p0[4] = {0, 0, 0, 0}, p1[4] = {0, 0, 0, 0};
    int i = beg;
    for (; i + 1 < end; i += 2) {
        int2 e0 = es[i], e1 = es[i + 1];
        float w0 = __int_as_float(e0.y), w1 = __int_as_float(e1.y);
        size_t r0 = ((size_t)e0.x << 7) + (lane << 2);
        size_t r1 = ((size_t)e1.x << 7) + (lane << 2);
        ushort4 x0 = *reinterpret_cast<const ushort4*>(V0 + r0);
        ushort4 x1 = *reinterpret_cast<const ushort4*>(V0 + r1);
        p0[0] += w0 * bf2f(x0.x); p0[1] += w0 * bf2f(x0.y);
        p0[2] += w0 * bf2f(x0.z); p0[3] += w0 * bf2f(x0.w);
        p1[0] += w1 * bf2f(x1.x); p1[1] += w1 * bf2f(x1.y);
        p1[2] += w1 * bf2f(x1.z); p1[3] += w1 * bf2f(x1.w);
    }
    if (i < end) {
        int2 e0 = es[i];
        float w0 = __int_as_float(e0.y);
        size_t r0 = ((size_t)e0.x << 7) + (lane << 2);
        ushort4 x0 = *reinterpret_cast<const ushort4*>(V0 + r0);
        p0[0] += w0 * bf2f(x0.x); p0[1] += w0 * bf2f(x0.y);
        p0[2] += w0 * bf2f(x0.z); p0[3] += w0 * bf2f(x0.w);
    }
    size_t ob = ((size_t)node << 7) + (lane << 2);
    ushort4 o0;
    o0.x = f2bf(p0[0] + p1[0]); o0.y = f2bf(p0[1] + p1[1]);
    o0.z = f2bf(p0[2] + p1[2]); o0.w = f2bf(p0[3] + p1[3]);
    *reinterpret_cast<ushort4*>(agg0 + ob) = o0;
}

// ---------------------------------------------------------------------------
// MFMA GEMM, 64x128 tile, 4 waves (2x2), 2x4 frags/wave, double-buffered LDS.
// A = [A0|A1|A2|A3] (N x 512 bf16, 4 row-major 128-col parts),
// B = Wb bf16 k-octet layout [K/8][Ntot][8].
// mode 0 (ru): col<128 -> rhb = bf16(sigmoid*h); col>=128 -> u = sigmoid (f32)
// mode 1 (c):  c = sigmoid; hn = u*h+(1-u)*c -> outf (+outf2), outb = bf16(hn)
// ---------------------------------------------------------------------------
__global__ __launch_bounds__(256) void gemm_mfma(
    const unsigned short* __restrict__ A0, const unsigned short* __restrict__ A1,
    const unsigned short* __restrict__ A2, const unsigned short* __restrict__ A3,
    const unsigned short* __restrict__ Wb, const float* __restrict__ bias,
    const float* __restrict__ hfull, const float* __restrict__ uin,
    unsigned short* __restrict__ outb, float* __restrict__ outf,
    float* __restrict__ outf2, int Nn, int Ntot, int mode) {
    __shared__ __align__(16) unsigned short Als[2][4 * 64 * 8];   // [buf][q][m][8]  4KB x2
    __shared__ __align__(16) unsigned short Bls[2][4 * 128 * 8];  // [buf][q][n][8]  8KB x2
    const unsigned short* parts[4] = {A0, A1, A2, A3};

    int tid = threadIdx.x;
    int row0 = blockIdx.x * 64;
    int n0c = blockIdx.y * 128;
    int lane = tid & 63;
    int w = tid >> 6;
    int wrow = (w & 1) << 5;       // 0 / 32
    int wcol = (w >> 1) << 6;      // 0 / 64
    int quad = lane >> 4, l16 = lane & 15;

    f32x4 acc[2][4];
    const f32x4 z4 = {0.f, 0.f, 0.f, 0.f};
#pragma unroll
    for (int mt = 0; mt < 2; ++mt)
#pragma unroll
        for (int nt = 0; nt < 4; ++nt) acc[mt][nt] = z4;

    // A stage: q = w (k-octet), m = lane (row); one issue per thread
    int growA = row0 + lane;
    if (growA >= Nn) growA = Nn - 1;
    // B stage: 2 rounds; round r: q = 2r + (tid>>7), n = tid&127
    int qB = tid >> 7, nB = tid & 127;

    auto stage = [&](int ks, int buf) {
        const unsigned short* ga = parts[ks >> 7] + ((size_t)growA << 7) + (ks & 127) + (w << 3);
        __builtin_amdgcn_global_load_lds(
            (const __attribute__((address_space(1))) void*)ga,
            (__attribute__((address_space(3))) void*)&Als[buf][((w << 6) + lane) << 3], 16, 0, 0);
#pragma unroll
        for (int r = 0; r < 2; ++r) {
            int q = 2 * r + qB;
            int koG = (ks >> 3) + q;
            const unsigned short* gb = Wb + ((size_t)(koG * Ntot + n0c + nB) << 3);
            __builtin_amdgcn_global_load_lds(
                (const __attribute__((address_space(1))) void*)gb,
                (__attribute__((address_space(3))) void*)&Bls[buf][((q << 7) + nB) << 3], 16, 0, 0);
        }
    };

    stage(0, 0);
    __syncthreads();
    int buf = 0;
    for (int ks = 0; ks < 512; ks += 32, buf ^= 1) {
        if (ks + 32 < 512) stage(ks + 32, buf ^ 1);

        bf16x8s af[2], bfr[4];
#pragma unroll
        for (int mt = 0; mt < 2; ++mt)
            af[mt] = *reinterpret_cast<const bf16x8s*>(
                &Als[buf][((quad << 6) + wrow + (mt << 4) + l16) << 3]);
#pragma unroll
        for (int nt = 0; nt < 4; ++nt)
            bfr[nt] = *reinterpret_cast<const bf16x8s*>(
                &Bls[buf][((quad << 7) + wcol + (nt << 4) + l16) << 3]);
#pragma unroll
        for (int mt = 0; mt < 2; ++mt)
#pragma unroll
            for (int nt = 0; nt < 4; ++nt)
                acc[mt][nt] = __builtin_amdgcn_mfma_f32_16x16x32_bf16(
                    af[mt], bfr[nt], acc[mt][nt], 0, 0, 0);
        __syncthreads();
    }

    // Epilogue: row = row0 + wrow + mt*16 + quad*4 + reg; col = n0c + wcol + nt*16 + l16
#pragma unroll
    for (int mt = 0; mt < 2; ++mt) {
#pragma unroll
        for (int reg = 0; reg < 4; ++reg) {
            int row = row0 + wrow + (mt << 4) + (quad << 2) + reg;
            if (row >= Nn) continue;
#pragma unroll
            for (int nt = 0; nt < 4; ++nt) {
                int col = n0c + wcol + (nt << 4) + l16;
                float val = acc[mt][nt][reg] + bias[col];
                if (mode == 0) {
                    float sg = sigmoidf_(val);
                    int c = col & 127;
                    size_t o = ((size_t)row << 7) + c;
                    if (col < 128)
                        outb[o] = f2bf(sg * hfull[o]);   // rh = r*h (bf16)
                    else
                        outf[o] = sg;                    // u (f32)
                } else {
                    float cv = sigmoidf_(val);
                    size_t o = ((size_t)row << 7) + col;
                    float uu = uin[o];
                    float hh = hfull[o];
                    float hn = uu * hh + (1.0f - uu) * cv;
                    outf[o] = hn;
                    if (outf2) outf2[o] = hn;
                    outb[o] = f2bf(hn);                  // next layer's xb
                }
            }
        }
    }
}

// ---------------------------------------------------------------------------
extern "C" void kernel_launch(void* const* d_in, const int* in_sizes, int n_in,
                              void* d_out, int out_size, void* d_ws, size_t ws_size,
                              hipStream_t stream) {
    const float* x      = (const float*)d_in[0];
    const float* hidden = (const float*)d_in[1];
    const int*   src    = (const int*)d_in[2];
    const int*   dst    = (const int*)d_in[3];
    const float* ew     = (const float*)d_in[4];
    const float* Wself  = (const float*)d_in[5];
    const float* Wneigh = (const float*)d_in[6];
    const float* bias   = (const float*)d_in[7];
    float* out = (float*)d_out;

    int N = in_sizes[0] / F;  // 50000
    int E = in_sizes[2];      // 800000
    size_t NF = (size_t)N * F;

    char* p = (char*)d_ws;
    auto alloc = [&](size_t bytes) { char* r = p; p += (bytes + 255) & ~255ull; return r; };
    unsigned short* xb0    = (unsigned short*)alloc(NF * 2);
    unsigned short* xb1    = (unsigned short*)alloc(NF * 2);
    unsigned short* hb     = (unsigned short*)alloc(2 * NF * 2);
    unsigned short* agg_xb = (unsigned short*)alloc(NF * 2);
    unsigned short* agg_hb = (unsigned short*)alloc(NF * 2);
    unsigned short* agg_rb = (unsigned short*)alloc(NF * 2);
    unsigned short* rhb    = (unsigned short*)alloc(NF * 2);
    float*          u      = (float*)alloc(NF * 4);
    unsigned short* W1b    = (unsigned short*)alloc(2 * 64 * 256 * 8 * 2);
    unsigned short* W2b    = (unsigned short*)alloc(2 * 64 * 128 * 8 * 2);
    int2*           es     = (int2*)alloc((size_t)E * 8);
    int*            cnt    = (int*)alloc((size_t)N * 4);
    int*            offs   = (int*)alloc(((size_t)N + 1) * 4);
    int*            cursor = (int*)alloc((size_t)N * 4);

    pack_w_bf16<<<dim3(1536), dim3(256), 0, stream>>>(Wself, Wneigh, W1b, W2b);
    cvt_bf16<<<dim3((int)(NF / 4 + 255) / 256, 1), dim3(256), 0, stream>>>(x, xb0, (int)(NF / 4));
    cvt_bf16<<<dim3((int)(2 * NF / 4 + 255) / 256, 1), dim3(256), 0, stream>>>(hidden, hb, (int)(2 * NF / 4));

    hipMemsetAsync(cnt, 0, (size_t)N * sizeof(int), stream);
    int eBlocks = (E + 255) / 256;
    hist_dst<<<dim3(eBlocks), dim3(256), 0, stream>>>(dst, cnt, E);
    scan_offs<<<dim3(1), dim3(1024), 0, stream>>>(cnt, offs, cursor, N);
    scatter_edges<<<dim3(eBlocks), dim3(256), 0, stream>>>(src, dst, ew, cursor, es, E);

    float* out_x  = out;
    float* out_h1 = out + NF;
    float* out_h2 = out + 2 * NF;

    int aggBlocks = (N + 7) / 8;
    int mBlocks = (N + 63) / 64;
    for (int l = 0; l < NLAYERS; ++l) {
        const unsigned short* xbL = (l == 0) ? xb0 : xb1;
        const unsigned short* hbL = hb + (size_t)l * NF;
        const float* hL = hidden + (size_t)l * NF;
        const float* biasL = bias + (size_t)l * 384;

        agg_csr2_b<<<dim3(aggBlocks), dim3(256), 0, stream>>>(xbL, hbL, es, offs,
                                                              agg_xb, agg_hb, N);

        gemm_mfma<<<dim3(mBlocks, 2), dim3(256), 0, stream>>>(
            xbL, hbL, agg_xb, agg_hb,
            W1b + (size_t)l * 64 * 256 * 8, biasL, hL, nullptr,
            rhb, u, nullptr, N, 256, 0);

        agg_csr1_b<<<dim3(aggBlocks), dim3(256), 0, stream>>>(rhb, es, offs, agg_rb, N);

        float* o1 = (l == 0) ? out_h1 : out_h2;
        float* o2 = (l == NLAYERS - 1) ? out_x : nullptr;
        unsigned short* xbN = (l == 0) ? xb1 : xb0;  // l==1's outb is a dead scratch
        gemm_mfma<<<dim3(mBlocks, 1), dim3(256), 0, stream>>>(
            xbL, rhb, agg_xb, agg_rb,
            W2b + (size_t)l * 64 * 128 * 8, biasL + 256, hL, u,
            xbN, o1, o2, N, 128, 1);
    }
}